// Round 5
// baseline (86.070 us; speedup 1.0000x reference)
//
#include <hip/hip_runtime.h>
#include <hip/hip_bf16.h>

// Attention: B=512, T=128, C=512, H=64. out[b,t,h] f32.
// R5: qkv gets a 4-deep software-pipelined x-load (explicit MLP).
//  1) wpack:  W (3x[64][512] f32) -> bf16 MFMA-fragment-packed into ws.
//  2) qkv:    QKV = X @ W^T, bf16 planes [3][65536][64] in ws.
//             16 rows/wave, acc[12] (48 VGPR) + pv[4] prefetch (32 VGPR),
//             __launch_bounds__(256,3); 1024 blocks.
//  3) attn:   per batch element: stage Q/K/V^T into swizzled LDS, QK^T,
//             in-register causal softmax (deferred norm), PV, f32 out.

#define TT 128
#define CC 512
#define HH 64

typedef __attribute__((ext_vector_type(8))) short bf16x8;
typedef __attribute__((ext_vector_type(8))) ushort u16x8;
typedef __attribute__((ext_vector_type(4))) float f32x4;

#define QKV_PLANE 4194304           // 65536*64 elems per plane
#define WPK_ELEMS 98304             // 3*64*512

__device__ __forceinline__ ushort f2bf(float f) {
    union { float f; unsigned u; } v; v.f = f;
    unsigned r = v.u + 0x7fffu + ((v.u >> 16) & 1u);  // RNE
    return (ushort)(r >> 16);
}

// ---- wpack: packed fragment p = ((nt*16+kt)*64 + lane)*8 + j, nt=w*4+nt4 ----
// value = W_w[h][c], h = nt4*16 + (lane&15), c = kt*32 + (lane>>4)*8 + j
__global__ void wpack_kernel(const float* __restrict__ wq,
                             const float* __restrict__ wk,
                             const float* __restrict__ wv,
                             ushort* __restrict__ wpk) {
    int p = blockIdx.x * 256 + threadIdx.x;   // 0..98303
    int j  = p & 7;
    int l  = (p >> 3) & 63;
    int kt = (p >> 9) & 15;
    int nt4 = (p >> 13) & 3;
    int w  = p >> 15;
    const float* src = (w == 0) ? wq : ((w == 1) ? wk : wv);
    int h = nt4 * 16 + (l & 15);
    int c = kt * 32 + ((l >> 4) << 3) + j;
    wpk[p] = f2bf(src[h * 512 + c]);
}

// ---- qkv: each wave computes 16 rows x 192 cols; 4096 waves ----
__launch_bounds__(256, 3)
__global__ void qkv_kernel(const float* __restrict__ x,
                           const ushort* __restrict__ wpk,
                           ushort* __restrict__ qkv) {
    const int tid  = threadIdx.x;
    const int wave = tid >> 6;
    const int lane = tid & 63;
    const int lq   = lane >> 4;
    const int lr   = lane & 15;
    const long row0 = ((long)blockIdx.x * 4 + wave) * 16;

    const float* xr = x + (row0 + lr) * CC + lq * 8;

    const f32x4 fzero = {0.f, 0.f, 0.f, 0.f};
    f32x4 acc[12];
    #pragma unroll
    for (int j = 0; j < 12; ++j) acc[j] = fzero;

    // 4-deep software pipeline on the x loads (static indices via full unroll)
    float4 pv0[4], pv1[4];
    #pragma unroll
    for (int i = 0; i < 4; ++i) {
        pv0[i] = *(const float4*)(xr + i * 32);
        pv1[i] = *(const float4*)(xr + i * 32 + 4);
    }

    #pragma unroll
    for (int kt = 0; kt < 16; ++kt) {
        float4 v0 = pv0[kt & 3];
        float4 v1 = pv1[kt & 3];
        if (kt + 4 < 16) {                       // issue 4 iterations ahead
            pv0[kt & 3] = *(const float4*)(xr + (kt + 4) * 32);
            pv1[kt & 3] = *(const float4*)(xr + (kt + 4) * 32 + 4);
        }
        bf16x8 a;
        a[0] = (short)f2bf(v0.x); a[1] = (short)f2bf(v0.y);
        a[2] = (short)f2bf(v0.z); a[3] = (short)f2bf(v0.w);
        a[4] = (short)f2bf(v1.x); a[5] = (short)f2bf(v1.y);
        a[6] = (short)f2bf(v1.z); a[7] = (short)f2bf(v1.w);
        const ushort* wb = wpk + kt * 512 + lane * 8;
        #pragma unroll
        for (int nt = 0; nt < 12; ++nt) {
            bf16x8 bb = *(const bf16x8*)(wb + nt * 8192);   // (nt*16)*512
            acc[nt] = __builtin_amdgcn_mfma_f32_16x16x32_bf16(a, bb, acc[nt], 0, 0, 0);
        }
    }

    #pragma unroll
    for (int nt = 0; nt < 12; ++nt)
        #pragma unroll
        for (int j = 0; j < 4; ++j) {
            long R = row0 + lq * 4 + j;
            int h = (nt & 3) * 16 + lr;
            qkv[(size_t)(nt >> 2) * QKV_PLANE + R * 64 + h] = f2bf(acc[nt][j]);
        }
}

// ---- attn: one block (4 waves) per batch element ----
__launch_bounds__(256)
__global__ void attn_kernel(const ushort* __restrict__ qkv,
                            float* __restrict__ out) {
    // 48 KB LDS -> 3 blocks/CU. ps overlays qs+ks in phase 3.
    __shared__ __align__(16) ushort sm[3 * 128 * 64];
    ushort* qs  = sm;                // [128][64]  swizzled: col ^ ((row&7)<<3)
    ushort* ks  = sm + 8192;         // [128][64]  swizzled
    ushort* vst = sm + 16384;        // [64][128]  V^T [h][t], swizzled on t
    ushort* ps  = sm;                // [128][128] P overlay, swizzled

    const int tid  = threadIdx.x;
    const int wave = tid >> 6;
    const int lane = tid & 63;
    const int lq   = lane >> 4;
    const int lr   = lane & 15;
    const int b    = blockIdx.x;
    const int row0 = wave * 32;

    const ushort* qp = qkv + (size_t)b * 8192;
    const ushort* kp = qkv + QKV_PLANE + (size_t)b * 8192;
    const ushort* vp = qkv + 2 * (size_t)QKV_PLANE + (size_t)b * 8192;

    // stage Q,K (row-major swizzled) and V transposed
    #pragma unroll
    for (int it = 0; it < 4; ++it) {
        int v = it * 256 + tid;          // ushort8 index 0..1023
        int r = v >> 3;
        int c = (v & 7) * 8;
        int sw = r * 64 + (c ^ ((r & 7) << 3));
        *(u16x8*)&qs[sw] = *(const u16x8*)(qp + v * 8);
        *(u16x8*)&ks[sw] = *(const u16x8*)(kp + v * 8);
        u16x8 v8 = *(const u16x8*)(vp + v * 8);
        #pragma unroll
        for (int k = 0; k < 8; ++k) {
            int h = c + k;
            vst[h * 128 + (r ^ ((h & 7) << 3))] = v8[k];
        }
    }
    __syncthreads();

    // ---------------- S = Q K^T, scale, causal softmax --------------------
    const f32x4 fzero = {0.f, 0.f, 0.f, 0.f};
    f32x4 s[2][8];
    #pragma unroll
    for (int i = 0; i < 2; ++i)
        #pragma unroll
        for (int j = 0; j < 8; ++j) s[i][j] = fzero;

    #pragma unroll
    for (int kt = 0; kt < 2; ++kt) {
        int h0 = kt * 32 + lq * 8;
        bf16x8 a[2];
        #pragma unroll
        for (int mt = 0; mt < 2; ++mt) {
            int t = row0 + mt * 16 + lr;
            a[mt] = *(const bf16x8*)&qs[t * 64 + (h0 ^ ((t & 7) << 3))];
        }
        #pragma unroll
        for (int nt = 0; nt < 8; ++nt) {
            int sc = nt * 16 + lr;
            bf16x8 bb = *(const bf16x8*)&ks[sc * 64 + (h0 ^ ((sc & 7) << 3))];
            s[0][nt] = __builtin_amdgcn_mfma_f32_16x16x32_bf16(a[0], bb, s[0][nt], 0, 0, 0);
            s[1][nt] = __builtin_amdgcn_mfma_f32_16x16x32_bf16(a[1], bb, s[1][nt], 0, 0, 0);
        }
    }

    float rinv[2][4];
    #pragma unroll
    for (int mt = 0; mt < 2; ++mt) {
        #pragma unroll
        for (int j = 0; j < 4; ++j) {
            int t = row0 + mt * 16 + lq * 4 + j;
            float m = -1e30f;
            #pragma unroll
            for (int nt = 0; nt < 8; ++nt) {
                int sc = nt * 16 + lr;
                float v = s[mt][nt][j] * 0.125f;
                v = (sc <= t) ? v : -1e30f;
                s[mt][nt][j] = v;
                m = fmaxf(m, v);
            }
            m = fmaxf(m, __shfl_xor(m, 1));
            m = fmaxf(m, __shfl_xor(m, 2));
            m = fmaxf(m, __shfl_xor(m, 4));
            m = fmaxf(m, __shfl_xor(m, 8));
            float sum = 0.f;
            #pragma unroll
            for (int nt = 0; nt < 8; ++nt) {
                float p = __expf(s[mt][nt][j] - m);
                s[mt][nt][j] = p;
                sum += p;
            }
            sum += __shfl_xor(sum, 1);
            sum += __shfl_xor(sum, 2);
            sum += __shfl_xor(sum, 4);
            sum += __shfl_xor(sum, 8);
            rinv[mt][j] = 1.0f / sum;              // deferred normalization
        }
    }

    __syncthreads();   // qs/ks reads done before P overlay writes

    #pragma unroll
    for (int mt = 0; mt < 2; ++mt)
        #pragma unroll
        for (int j = 0; j < 4; ++j) {
            int t = row0 + mt * 16 + lq * 4 + j;
            #pragma unroll
            for (int nt = 0; nt < 8; ++nt) {
                int sc = nt * 16 + lr;
                ps[t * 128 + (sc ^ ((t & 7) << 3))] = f2bf(s[mt][nt][j]);
            }
        }
    __syncthreads();

    // ---------------- O = P V --------------------------------------------
    f32x4 o[2][4];
    #pragma unroll
    for (int i = 0; i < 2; ++i)
        #pragma unroll
        for (int j = 0; j < 4; ++j) o[i][j] = fzero;

    #pragma unroll
    for (int ksv = 0; ksv < 4; ++ksv) {
        int s0 = ksv * 32 + lq * 8;
        bf16x8 a[2];
        #pragma unroll
        for (int mt = 0; mt < 2; ++mt) {
            int t = row0 + mt * 16 + lr;
            a[mt] = *(const bf16x8*)&ps[t * 128 + (s0 ^ ((t & 7) << 3))];
        }
        #pragma unroll
        for (int nt = 0; nt < 4; ++nt) {
            int h = nt * 16 + lr;
            bf16x8 bb = *(const bf16x8*)&vst[h * 128 + (s0 ^ ((h & 7) << 3))];
            o[0][nt] = __builtin_amdgcn_mfma_f32_16x16x32_bf16(a[0], bb, o[0][nt], 0, 0, 0);
            o[1][nt] = __builtin_amdgcn_mfma_f32_16x16x32_bf16(a[1], bb, o[1][nt], 0, 0, 0);
        }
    }

    float* ob = out + (size_t)b * (TT * HH);
    #pragma unroll
    for (int mt = 0; mt < 2; ++mt)
        #pragma unroll
        for (int nt = 0; nt < 4; ++nt)
            #pragma unroll
            for (int j = 0; j < 4; ++j) {
                int t = row0 + mt * 16 + lq * 4 + j;
                int h = nt * 16 + lr;
                ob[t * HH + h] = o[mt][nt][j] * rinv[mt][j];
            }
}

extern "C" void kernel_launch(void* const* d_in, const int* in_sizes, int n_in,
                              void* d_out, int out_size, void* d_ws, size_t ws_size,
                              hipStream_t stream) {
    const float* x  = (const float*)d_in[0];
    const float* wq = (const float*)d_in[1];
    const float* wk = (const float*)d_in[2];
    const float* wv = (const float*)d_in[3];
    float* o = (float*)d_out;

    // ws layout: [0, 192K)   packed W fragments (bf16)
    //            [192K, +24M) QKV planes bf16 [3][65536][64]
    ushort* wpk = (ushort*)d_ws;
    ushort* qkv = (ushort*)((char*)d_ws + WPK_ELEMS * 2);

    (void)in_sizes; (void)n_in; (void)out_size; (void)ws_size;

    wpack_kernel<<<384, 256, 0, stream>>>(wq, wk, wv, wpk);
    qkv_kernel<<<1024, 256, 0, stream>>>(x, wpk, qkv);
    attn_kernel<<<512, 256, 0, stream>>>(qkv, o);
}

// Round 6
// 76.136 us; speedup vs baseline: 1.1305x; 1.1305x over previous
//
#include <hip/hip_runtime.h>
#include <hip/hip_bf16.h>

// Attention: B=512, T=128, C=512, H=64. out[b,t,h] f32.
// R6: qkv restructured: 32 rows/wave (amortize W over 2 m-tiles),
//     register double-buffered W fragments + 2-deep x prefetch,
//     __launch_bounds__(256,2) for register headroom. 512 blocks.
//  1) wpack: W (3x[64][512] f32) -> bf16 MFMA-fragment-packed into ws.
//  2) qkv:   QKV = X @ W^T -> bf16 planes [3][65536][64] in ws.
//  3) attn:  per batch element: stage Q/K/V^T into swizzled LDS, QK^T,
//            in-register causal softmax (deferred norm), PV, f32 out.

#define TT 128
#define CC 512
#define HH 64

typedef __attribute__((ext_vector_type(8))) short bf16x8;
typedef __attribute__((ext_vector_type(8))) ushort u16x8;
typedef __attribute__((ext_vector_type(4))) float f32x4;

#define QKV_PLANE 4194304           // 65536*64 elems per plane
#define WPK_ELEMS 98304             // 3*64*512

__device__ __forceinline__ ushort f2bf(float f) {
    union { float f; unsigned u; } v; v.f = f;
    unsigned r = v.u + 0x7fffu + ((v.u >> 16) & 1u);  // RNE
    return (ushort)(r >> 16);
}

// ---- wpack: packed fragment p = ((nt*16+kt)*64 + lane)*8 + j, nt=w*4+nt4 ----
// value = W_w[h][c], h = nt4*16 + (lane&15), c = kt*32 + (lane>>4)*8 + j
__global__ void wpack_kernel(const float* __restrict__ wq,
                             const float* __restrict__ wk,
                             const float* __restrict__ wv,
                             ushort* __restrict__ wpk) {
    int p = blockIdx.x * 256 + threadIdx.x;   // 0..98303
    int j  = p & 7;
    int l  = (p >> 3) & 63;
    int kt = (p >> 9) & 15;
    int nt4 = (p >> 13) & 3;
    int w  = p >> 15;
    const float* src = (w == 0) ? wq : ((w == 1) ? wk : wv);
    int h = nt4 * 16 + (l & 15);
    int c = kt * 32 + ((l >> 4) << 3) + j;
    wpk[p] = f2bf(src[h * 512 + c]);
}

// ---- qkv: each wave computes 32 rows x 192 cols; 2048 waves, 512 blocks ----
__launch_bounds__(256, 2)
__global__ void qkv_kernel(const float* __restrict__ x,
                           const ushort* __restrict__ wpk,
                           ushort* __restrict__ qkv) {
    const int tid  = threadIdx.x;
    const int wave = tid >> 6;
    const int lane = tid & 63;
    const int lq   = lane >> 4;
    const int lr   = lane & 15;
    const long row0 = ((long)blockIdx.x * 4 + wave) * 32;

    const float* xr0 = x + (row0 + lr) * CC + lq * 8;        // m-tile 0
    const float* xr1 = xr0 + 16 * CC;                        // m-tile 1
    const ushort* wb = wpk + lane * 8;

    const f32x4 fzero = {0.f, 0.f, 0.f, 0.f};
    f32x4 acc[2][12];                                        // 96 VGPR
    #pragma unroll
    for (int i = 0; i < 2; ++i)
        #pragma unroll
        for (int j = 0; j < 12; ++j) acc[i][j] = fzero;

    bf16x8 Wf[2][12];                                        // 96 VGPR dbuf
    #pragma unroll
    for (int nt = 0; nt < 12; ++nt)
        Wf[0][nt] = *(const bf16x8*)(wb + nt * 8192);        // W(kt=0)

    float4 xp[2][4];                                         // 32 VGPR, 2-deep
    #pragma unroll
    for (int s = 0; s < 2; ++s) {
        xp[s][0] = *(const float4*)(xr0 + s * 32);
        xp[s][1] = *(const float4*)(xr0 + s * 32 + 4);
        xp[s][2] = *(const float4*)(xr1 + s * 32);
        xp[s][3] = *(const float4*)(xr1 + s * 32 + 4);
    }

    #pragma unroll
    for (int kt = 0; kt < 16; ++kt) {
        const int cur = kt & 1;
        // issue next W tile into the other buffer (hidden under this iter)
        if (kt + 1 < 16) {
            #pragma unroll
            for (int nt = 0; nt < 12; ++nt)
                Wf[cur ^ 1][nt] = *(const bf16x8*)(wb + (kt + 1) * 512 + nt * 8192);
        }
        // convert current x slot to bf16 fragments
        bf16x8 a0, a1;
        a0[0] = (short)f2bf(xp[cur][0].x); a0[1] = (short)f2bf(xp[cur][0].y);
        a0[2] = (short)f2bf(xp[cur][0].z); a0[3] = (short)f2bf(xp[cur][0].w);
        a0[4] = (short)f2bf(xp[cur][1].x); a0[5] = (short)f2bf(xp[cur][1].y);
        a0[6] = (short)f2bf(xp[cur][1].z); a0[7] = (short)f2bf(xp[cur][1].w);
        a1[0] = (short)f2bf(xp[cur][2].x); a1[1] = (short)f2bf(xp[cur][2].y);
        a1[2] = (short)f2bf(xp[cur][2].z); a1[3] = (short)f2bf(xp[cur][2].w);
        a1[4] = (short)f2bf(xp[cur][3].x); a1[5] = (short)f2bf(xp[cur][3].y);
        a1[6] = (short)f2bf(xp[cur][3].z); a1[7] = (short)f2bf(xp[cur][3].w);
        // reload this x slot for kt+2 (2 iterations of flight time)
        if (kt + 2 < 16) {
            xp[cur][0] = *(const float4*)(xr0 + (kt + 2) * 32);
            xp[cur][1] = *(const float4*)(xr0 + (kt + 2) * 32 + 4);
            xp[cur][2] = *(const float4*)(xr1 + (kt + 2) * 32);
            xp[cur][3] = *(const float4*)(xr1 + (kt + 2) * 32 + 4);
        }
        // 24 MFMAs on the current W buffer
        #pragma unroll
        for (int nt = 0; nt < 12; ++nt) {
            acc[0][nt] = __builtin_amdgcn_mfma_f32_16x16x32_bf16(a0, Wf[cur][nt], acc[0][nt], 0, 0, 0);
            acc[1][nt] = __builtin_amdgcn_mfma_f32_16x16x32_bf16(a1, Wf[cur][nt], acc[1][nt], 0, 0, 0);
        }
    }

    #pragma unroll
    for (int mt = 0; mt < 2; ++mt)
        #pragma unroll
        for (int nt = 0; nt < 12; ++nt)
            #pragma unroll
            for (int j = 0; j < 4; ++j) {
                long R = row0 + mt * 16 + lq * 4 + j;
                int h = (nt & 3) * 16 + lr;
                qkv[(size_t)(nt >> 2) * QKV_PLANE + R * 64 + h] = f2bf(acc[mt][nt][j]);
            }
}

// ---- attn: one block (4 waves) per batch element ----
__launch_bounds__(256)
__global__ void attn_kernel(const ushort* __restrict__ qkv,
                            float* __restrict__ out) {
    // 48 KB LDS -> 3 blocks/CU. ps overlays qs+ks in phase 3.
    __shared__ __align__(16) ushort sm[3 * 128 * 64];
    ushort* qs  = sm;                // [128][64]  swizzled: col ^ ((row&7)<<3)
    ushort* ks  = sm + 8192;         // [128][64]  swizzled
    ushort* vst = sm + 16384;        // [64][128]  V^T [h][t], swizzled on t
    ushort* ps  = sm;                // [128][128] P overlay, swizzled

    const int tid  = threadIdx.x;
    const int wave = tid >> 6;
    const int lane = tid & 63;
    const int lq   = lane >> 4;
    const int lr   = lane & 15;
    const int b    = blockIdx.x;
    const int row0 = wave * 32;

    const ushort* qp = qkv + (size_t)b * 8192;
    const ushort* kp = qkv + QKV_PLANE + (size_t)b * 8192;
    const ushort* vp = qkv + 2 * (size_t)QKV_PLANE + (size_t)b * 8192;

    // stage Q,K (row-major swizzled) and V transposed
    #pragma unroll
    for (int it = 0; it < 4; ++it) {
        int v = it * 256 + tid;          // ushort8 index 0..1023
        int r = v >> 3;
        int c = (v & 7) * 8;
        int sw = r * 64 + (c ^ ((r & 7) << 3));
        *(u16x8*)&qs[sw] = *(const u16x8*)(qp + v * 8);
        *(u16x8*)&ks[sw] = *(const u16x8*)(kp + v * 8);
        u16x8 v8 = *(const u16x8*)(vp + v * 8);
        #pragma unroll
        for (int k = 0; k < 8; ++k) {
            int h = c + k;
            vst[h * 128 + (r ^ ((h & 7) << 3))] = v8[k];
        }
    }
    __syncthreads();

    // ---------------- S = Q K^T, scale, causal softmax --------------------
    const f32x4 fzero = {0.f, 0.f, 0.f, 0.f};
    f32x4 s[2][8];
    #pragma unroll
    for (int i = 0; i < 2; ++i)
        #pragma unroll
        for (int j = 0; j < 8; ++j) s[i][j] = fzero;

    #pragma unroll
    for (int kt = 0; kt < 2; ++kt) {
        int h0 = kt * 32 + lq * 8;
        bf16x8 a[2];
        #pragma unroll
        for (int mt = 0; mt < 2; ++mt) {
            int t = row0 + mt * 16 + lr;
            a[mt] = *(const bf16x8*)&qs[t * 64 + (h0 ^ ((t & 7) << 3))];
        }
        #pragma unroll
        for (int nt = 0; nt < 8; ++nt) {
            int sc = nt * 16 + lr;
            bf16x8 bb = *(const bf16x8*)&ks[sc * 64 + (h0 ^ ((sc & 7) << 3))];
            s[0][nt] = __builtin_amdgcn_mfma_f32_16x16x32_bf16(a[0], bb, s[0][nt], 0, 0, 0);
            s[1][nt] = __builtin_amdgcn_mfma_f32_16x16x32_bf16(a[1], bb, s[1][nt], 0, 0, 0);
        }
    }

    float rinv[2][4];
    #pragma unroll
    for (int mt = 0; mt < 2; ++mt) {
        #pragma unroll
        for (int j = 0; j < 4; ++j) {
            int t = row0 + mt * 16 + lq * 4 + j;
            float m = -1e30f;
            #pragma unroll
            for (int nt = 0; nt < 8; ++nt) {
                int sc = nt * 16 + lr;
                float v = s[mt][nt][j] * 0.125f;
                v = (sc <= t) ? v : -1e30f;
                s[mt][nt][j] = v;
                m = fmaxf(m, v);
            }
            m = fmaxf(m, __shfl_xor(m, 1));
            m = fmaxf(m, __shfl_xor(m, 2));
            m = fmaxf(m, __shfl_xor(m, 4));
            m = fmaxf(m, __shfl_xor(m, 8));
            float sum = 0.f;
            #pragma unroll
            for (int nt = 0; nt < 8; ++nt) {
                float p = __expf(s[mt][nt][j] - m);
                s[mt][nt][j] = p;
                sum += p;
            }
            sum += __shfl_xor(sum, 1);
            sum += __shfl_xor(sum, 2);
            sum += __shfl_xor(sum, 4);
            sum += __shfl_xor(sum, 8);
            rinv[mt][j] = 1.0f / sum;              // deferred normalization
        }
    }

    __syncthreads();   // qs/ks reads done before P overlay writes

    #pragma unroll
    for (int mt = 0; mt < 2; ++mt)
        #pragma unroll
        for (int j = 0; j < 4; ++j) {
            int t = row0 + mt * 16 + lq * 4 + j;
            #pragma unroll
            for (int nt = 0; nt < 8; ++nt) {
                int sc = nt * 16 + lr;
                ps[t * 128 + (sc ^ ((t & 7) << 3))] = f2bf(s[mt][nt][j]);
            }
        }
    __syncthreads();

    // ---------------- O = P V --------------------------------------------
    f32x4 o[2][4];
    #pragma unroll
    for (int i = 0; i < 2; ++i)
        #pragma unroll
        for (int j = 0; j < 4; ++j) o[i][j] = fzero;

    #pragma unroll
    for (int ksv = 0; ksv < 4; ++ksv) {
        int s0 = ksv * 32 + lq * 8;
        bf16x8 a[2];
        #pragma unroll
        for (int mt = 0; mt < 2; ++mt) {
            int t = row0 + mt * 16 + lr;
            a[mt] = *(const bf16x8*)&ps[t * 128 + (s0 ^ ((t & 7) << 3))];
        }
        #pragma unroll
        for (int nt = 0; nt < 4; ++nt) {
            int h = nt * 16 + lr;
            bf16x8 bb = *(const bf16x8*)&vst[h * 128 + (s0 ^ ((h & 7) << 3))];
            o[0][nt] = __builtin_amdgcn_mfma_f32_16x16x32_bf16(a[0], bb, o[0][nt], 0, 0, 0);
            o[1][nt] = __builtin_amdgcn_mfma_f32_16x16x32_bf16(a[1], bb, o[1][nt], 0, 0, 0);
        }
    }

    float* ob = out + (size_t)b * (TT * HH);
    #pragma unroll
    for (int mt = 0; mt < 2; ++mt)
        #pragma unroll
        for (int nt = 0; nt < 4; ++nt)
            #pragma unroll
            for (int j = 0; j < 4; ++j) {
                int t = row0 + mt * 16 + lq * 4 + j;
                int h = nt * 16 + lr;
                ob[t * HH + h] = o[mt][nt][j] * rinv[mt][j];
            }
}

extern "C" void kernel_launch(void* const* d_in, const int* in_sizes, int n_in,
                              void* d_out, int out_size, void* d_ws, size_t ws_size,
                              hipStream_t stream) {
    const float* x  = (const float*)d_in[0];
    const float* wq = (const float*)d_in[1];
    const float* wk = (const float*)d_in[2];
    const float* wv = (const float*)d_in[3];
    float* o = (float*)d_out;

    // ws layout: [0, 192K)   packed W fragments (bf16)
    //            [192K, +24M) QKV planes bf16 [3][65536][64]
    ushort* wpk = (ushort*)d_ws;
    ushort* qkv = (ushort*)((char*)d_ws + WPK_ELEMS * 2);

    (void)in_sizes; (void)n_in; (void)out_size; (void)ws_size;

    wpack_kernel<<<384, 256, 0, stream>>>(wq, wk, wv, wpk);
    qkv_kernel<<<512, 256, 0, stream>>>(x, wpk, qkv);
    attn_kernel<<<512, 256, 0, stream>>>(qkv, o);
}

// Round 7
// 48.680 us; speedup vs baseline: 1.7681x; 1.5640x over previous
//
#include <hip/hip_runtime.h>
#include <hip/hip_bf16.h>

// Attention: B=512, T=128, C=512, H=64. out[b,t,h] f32.
// R7: qkv rebuilt on the m97 GEMM structure: global_load_lds async staging,
//     LDS-shared W (fragment-packed), double-buffered 2-barrier K-loop,
//     4 blocks/CU. x staged f32 with XOR-swizzle via pre-swizzled source.
//  1) wpack: W -> bf16 fragments in (kt,nt,lane,j) order (chunk-contiguous).
//  2) qkv:   QKV = X @ W^T -> bf16 planes [3][65536][64] in ws.
//  3) attn:  per batch element: stage Q/K/V^T into swizzled LDS, QK^T,
//            in-register causal softmax (deferred norm), PV, f32 out.

#define TT 128
#define CC 512
#define HH 64

typedef __attribute__((ext_vector_type(8))) short bf16x8;
typedef __attribute__((ext_vector_type(8))) ushort u16x8;
typedef __attribute__((ext_vector_type(4))) float f32x4;

#define QKV_PLANE 4194304           // 65536*64 elems per plane
#define WPK_ELEMS 98304             // 3*64*512

__device__ __forceinline__ ushort f2bf(float f) {
    union { float f; unsigned u; } v; v.f = f;
    unsigned r = v.u + 0x7fffu + ((v.u >> 16) & 1u);  // RNE
    return (ushort)(r >> 16);
}

__device__ __forceinline__ void gload_lds16(const void* g, void* l) {
    __builtin_amdgcn_global_load_lds(
        (const __attribute__((address_space(1))) unsigned int*)g,
        (__attribute__((address_space(3))) unsigned int*)l, 16, 0, 0);
}

// ---- wpack: p = ((kt*12 + nt)*64 + lane)*8 + j  (chunk-contiguous) ----
// value = W_{nt>>2}[h][c], h = (nt&3)*16 + (lane&15), c = kt*32 + (lane>>4)*8 + j
__global__ void wpack_kernel(const float* __restrict__ wq,
                             const float* __restrict__ wk,
                             const float* __restrict__ wv,
                             ushort* __restrict__ wpk) {
    int p = blockIdx.x * 256 + threadIdx.x;   // 0..98303
    int j  = p & 7;
    int l  = (p >> 3) & 63;
    int nt = (p >> 9) % 12;
    int kt = p / (12 * 512);
    int w  = nt >> 2;
    const float* src = (w == 0) ? wq : ((w == 1) ? wk : wv);
    int h = (nt & 3) * 16 + (l & 15);
    int c = kt * 32 + ((l >> 4) << 3) + j;
    wpk[p] = f2bf(src[h * 512 + c]);
}

// ---- qkv: block = 4 waves, 64 rows x 192 cols; 1024 blocks = 4/CU ----
__launch_bounds__(256, 4)
__global__ void qkv_kernel(const float* __restrict__ x,
                           const ushort* __restrict__ wpk,
                           ushort* __restrict__ qkv) {
    // double-buffered: W 2x12KB + x 2x8KB = 40 KB
    __shared__ __align__(16) ushort wsw[2 * 6144];
    __shared__ __align__(16) float  wsx[2 * 2048];

    const int tid  = threadIdx.x;
    const int wave = tid >> 6;
    const int lane = tid & 63;
    const int lq   = lane >> 4;
    const int lr   = lane & 15;
    const long rowB = (long)blockIdx.x * 64;      // block's first row

    const f32x4 fzero = {0.f, 0.f, 0.f, 0.f};
    f32x4 acc[12];
    #pragma unroll
    for (int j = 0; j < 12; ++j) acc[j] = fzero;

    // ---- staging helper (inlined twice) ----
    auto stage = [&](int kt, int s) {
        // W slab: 12288 B, wave covers [wave*3072, +3072) in 3 passes of 1024 B
        const char* wsrc = (const char*)(wpk + kt * 6144);
        #pragma unroll
        for (int p = 0; p < 3; ++p) {
            int off = wave * 3072 + p * 1024;                 // uniform
            gload_lds16(wsrc + off + lane * 16,
                        (char*)wsw + s * 12288 + off);
        }
        // x slab: 8192 B = 64 rows x 128 B, swizzled source (slot ^ (row&7))
        #pragma unroll
        for (int p = 0; p < 2; ++p) {
            int uoff = wave * 2048 + p * 1024;                // uniform
            int off  = uoff + lane * 16;                      // per-lane
            int row  = off >> 7;
            int slot = (off >> 4) & 7;
            int g    = slot ^ (row & 7);
            const float* src = x + (rowB + row) * CC + kt * 32 + g * 4;
            gload_lds16(src, (char*)wsx + s * 8192 + uoff);
        }
    };

    stage(0, 0);
    __syncthreads();

    const int r = wave * 16 + lr;          // block-local row this lane reads
    for (int kt = 0; kt < 16; ++kt) {
        const int cur = kt & 1;
        if (kt + 1 < 16) stage(kt + 1, cur ^ 1);

        // A fragment: 8 floats from swizzled x slab, convert to bf16
        const float* xs = wsx + cur * 2048;
        int s0 = (lq * 2) ^ (r & 7);
        int s1 = (lq * 2 + 1) ^ (r & 7);
        f32x4 alo = *(const f32x4*)(xs + r * 32 + s0 * 4);
        f32x4 ahi = *(const f32x4*)(xs + r * 32 + s1 * 4);
        bf16x8 a;
        a[0] = (short)f2bf(alo[0]); a[1] = (short)f2bf(alo[1]);
        a[2] = (short)f2bf(alo[2]); a[3] = (short)f2bf(alo[3]);
        a[4] = (short)f2bf(ahi[0]); a[5] = (short)f2bf(ahi[1]);
        a[6] = (short)f2bf(ahi[2]); a[7] = (short)f2bf(ahi[3]);

        const ushort* wf = wsw + cur * 6144;
        #pragma unroll
        for (int nt = 0; nt < 12; ++nt) {
            bf16x8 bb = *(const bf16x8*)(wf + (nt * 64 + lane) * 8);
            acc[nt] = __builtin_amdgcn_mfma_f32_16x16x32_bf16(a, bb, acc[nt], 0, 0, 0);
        }
        __syncthreads();
    }

    #pragma unroll
    for (int nt = 0; nt < 12; ++nt)
        #pragma unroll
        for (int j = 0; j < 4; ++j) {
            long R = rowB + wave * 16 + lq * 4 + j;
            int h = (nt & 3) * 16 + lr;
            qkv[(size_t)(nt >> 2) * QKV_PLANE + R * 64 + h] = f2bf(acc[nt][j]);
        }
}

// ---- attn: one block (4 waves) per batch element ----
__launch_bounds__(256)
__global__ void attn_kernel(const ushort* __restrict__ qkv,
                            float* __restrict__ out) {
    // 48 KB LDS -> 3 blocks/CU. ps overlays qs+ks in phase 3.
    __shared__ __align__(16) ushort sm[3 * 128 * 64];
    ushort* qs  = sm;                // [128][64]  swizzled: col ^ ((row&7)<<3)
    ushort* ks  = sm + 8192;         // [128][64]  swizzled
    ushort* vst = sm + 16384;        // [64][128]  V^T [h][t], swizzled on t
    ushort* ps  = sm;                // [128][128] P overlay, swizzled

    const int tid  = threadIdx.x;
    const int wave = tid >> 6;
    const int lane = tid & 63;
    const int lq   = lane >> 4;
    const int lr   = lane & 15;
    const int b    = blockIdx.x;
    const int row0 = wave * 32;

    const ushort* qp = qkv + (size_t)b * 8192;
    const ushort* kp = qkv + QKV_PLANE + (size_t)b * 8192;
    const ushort* vp = qkv + 2 * (size_t)QKV_PLANE + (size_t)b * 8192;

    // stage Q,K (row-major swizzled) and V transposed
    #pragma unroll
    for (int it = 0; it < 4; ++it) {
        int v = it * 256 + tid;          // ushort8 index 0..1023
        int r = v >> 3;
        int c = (v & 7) * 8;
        int sw = r * 64 + (c ^ ((r & 7) << 3));
        *(u16x8*)&qs[sw] = *(const u16x8*)(qp + v * 8);
        *(u16x8*)&ks[sw] = *(const u16x8*)(kp + v * 8);
        u16x8 v8 = *(const u16x8*)(vp + v * 8);
        #pragma unroll
        for (int k = 0; k < 8; ++k) {
            int h = c + k;
            vst[h * 128 + (r ^ ((h & 7) << 3))] = v8[k];
        }
    }
    __syncthreads();

    // ---------------- S = Q K^T, scale, causal softmax --------------------
    const f32x4 fzero = {0.f, 0.f, 0.f, 0.f};
    f32x4 s[2][8];
    #pragma unroll
    for (int i = 0; i < 2; ++i)
        #pragma unroll
        for (int j = 0; j < 8; ++j) s[i][j] = fzero;

    #pragma unroll
    for (int kt = 0; kt < 2; ++kt) {
        int h0 = kt * 32 + lq * 8;
        bf16x8 a[2];
        #pragma unroll
        for (int mt = 0; mt < 2; ++mt) {
            int t = row0 + mt * 16 + lr;
            a[mt] = *(const bf16x8*)&qs[t * 64 + (h0 ^ ((t & 7) << 3))];
        }
        #pragma unroll
        for (int nt = 0; nt < 8; ++nt) {
            int sc = nt * 16 + lr;
            bf16x8 bb = *(const bf16x8*)&ks[sc * 64 + (h0 ^ ((sc & 7) << 3))];
            s[0][nt] = __builtin_amdgcn_mfma_f32_16x16x32_bf16(a[0], bb, s[0][nt], 0, 0, 0);
            s[1][nt] = __builtin_amdgcn_mfma_f32_16x16x32_bf16(a[1], bb, s[1][nt], 0, 0, 0);
        }
    }

    float rinv[2][4];
    #pragma unroll
    for (int mt = 0; mt < 2; ++mt) {
        #pragma unroll
        for (int j = 0; j < 4; ++j) {
            int t = row0 + mt * 16 + lq * 4 + j;
            float m = -1e30f;
            #pragma unroll
            for (int nt = 0; nt < 8; ++nt) {
                int sc = nt * 16 + lr;
                float v = s[mt][nt][j] * 0.125f;
                v = (sc <= t) ? v : -1e30f;
                s[mt][nt][j] = v;
                m = fmaxf(m, v);
            }
            m = fmaxf(m, __shfl_xor(m, 1));
            m = fmaxf(m, __shfl_xor(m, 2));
            m = fmaxf(m, __shfl_xor(m, 4));
            m = fmaxf(m, __shfl_xor(m, 8));
            float sum = 0.f;
            #pragma unroll
            for (int nt = 0; nt < 8; ++nt) {
                float p = __expf(s[mt][nt][j] - m);
                s[mt][nt][j] = p;
                sum += p;
            }
            sum += __shfl_xor(sum, 1);
            sum += __shfl_xor(sum, 2);
            sum += __shfl_xor(sum, 4);
            sum += __shfl_xor(sum, 8);
            rinv[mt][j] = 1.0f / sum;              // deferred normalization
        }
    }

    __syncthreads();   // qs/ks reads done before P overlay writes

    #pragma unroll
    for (int mt = 0; mt < 2; ++mt)
        #pragma unroll
        for (int j = 0; j < 4; ++j) {
            int t = row0 + mt * 16 + lq * 4 + j;
            #pragma unroll
            for (int nt = 0; nt < 8; ++nt) {
                int sc = nt * 16 + lr;
                ps[t * 128 + (sc ^ ((t & 7) << 3))] = f2bf(s[mt][nt][j]);
            }
        }
    __syncthreads();

    // ---------------- O = P V --------------------------------------------
    f32x4 o[2][4];
    #pragma unroll
    for (int i = 0; i < 2; ++i)
        #pragma unroll
        for (int j = 0; j < 4; ++j) o[i][j] = fzero;

    #pragma unroll
    for (int ksv = 0; ksv < 4; ++ksv) {
        int s0 = ksv * 32 + lq * 8;
        bf16x8 a[2];
        #pragma unroll
        for (int mt = 0; mt < 2; ++mt) {
            int t = row0 + mt * 16 + lr;
            a[mt] = *(const bf16x8*)&ps[t * 128 + (s0 ^ ((t & 7) << 3))];
        }
        #pragma unroll
        for (int nt = 0; nt < 4; ++nt) {
            int h = nt * 16 + lr;
            bf16x8 bb = *(const bf16x8*)&vst[h * 128 + (s0 ^ ((h & 7) << 3))];
            o[0][nt] = __builtin_amdgcn_mfma_f32_16x16x32_bf16(a[0], bb, o[0][nt], 0, 0, 0);
            o[1][nt] = __builtin_amdgcn_mfma_f32_16x16x32_bf16(a[1], bb, o[1][nt], 0, 0, 0);
        }
    }

    float* ob = out + (size_t)b * (TT * HH);
    #pragma unroll
    for (int mt = 0; mt < 2; ++mt)
        #pragma unroll
        for (int nt = 0; nt < 4; ++nt)
            #pragma unroll
            for (int j = 0; j < 4; ++j) {
                int t = row0 + mt * 16 + lq * 4 + j;
                int h = nt * 16 + lr;
                ob[t * HH + h] = o[mt][nt][j] * rinv[mt][j];
            }
}

extern "C" void kernel_launch(void* const* d_in, const int* in_sizes, int n_in,
                              void* d_out, int out_size, void* d_ws, size_t ws_size,
                              hipStream_t stream) {
    const float* x  = (const float*)d_in[0];
    const float* wq = (const float*)d_in[1];
    const float* wk = (const float*)d_in[2];
    const float* wv = (const float*)d_in[3];
    float* o = (float*)d_out;

    // ws layout: [0, 192K)   packed W fragments (bf16)
    //            [192K, +24M) QKV planes bf16 [3][65536][64]
    ushort* wpk = (ushort*)d_ws;
    ushort* qkv = (ushort*)((char*)d_ws + WPK_ELEMS * 2);

    (void)in_sizes; (void)n_in; (void)out_size; (void)ws_size;

    wpack_kernel<<<384, 256, 0, stream>>>(wq, wk, wv, wpk);
    qkv_kernel<<<1024, 256, 0, stream>>>(x, wpk, qkv);
    attn_kernel<<<512, 256, 0, stream>>>(qkv, o);
}

// Round 8
// 38.726 us; speedup vs baseline: 2.2225x; 1.2570x over previous
//
#include <hip/hip_runtime.h>
#include <hip/hip_bf16.h>

// Attention: B=512, T=128, C=512, H=64. out[b,t,h] f32.
// R8: fully fused. One block = one batch element (128 rows), 8 waves,
// 16 rows/wave. Projection uses the R7 m97-structure: async global_load_lds
// staging of W (fragment-packed) + x (f32, XOR-swizzled via pre-swizzled
// source), double-buffered, 16 k-chunks. QKV goes straight to swizzled LDS
// (union with the staging buffers -> 56 KB, 2 blocks/CU), then QK^T ->
// in-register causal softmax (deferred norm) -> PV -> f32 out. No QKV
// round-trip through HBM.

#define TT 128
#define CC 512
#define HH 64

typedef __attribute__((ext_vector_type(8))) short bf16x8;
typedef __attribute__((ext_vector_type(4))) float f32x4;

#define WPK_ELEMS 98304             // 3*64*512

__device__ __forceinline__ ushort f2bf(float f) {
    union { float f; unsigned u; } v; v.f = f;
    unsigned r = v.u + 0x7fffu + ((v.u >> 16) & 1u);  // RNE
    return (ushort)(r >> 16);
}

__device__ __forceinline__ void gload_lds16(const void* g, void* l) {
    __builtin_amdgcn_global_load_lds(
        (const __attribute__((address_space(1))) unsigned int*)g,
        (__attribute__((address_space(3))) unsigned int*)l, 16, 0, 0);
}

// ---- wpack: p = ((kt*12 + nt)*64 + lane)*8 + j  (chunk-contiguous) ----
// value = W_{nt>>2}[h][c], h = (nt&3)*16 + (lane&15), c = kt*32 + (lane>>4)*8 + j
__global__ void wpack_kernel(const float* __restrict__ wq,
                             const float* __restrict__ wk,
                             const float* __restrict__ wv,
                             ushort* __restrict__ wpk) {
    int p = blockIdx.x * 256 + threadIdx.x;   // 0..98303
    int j  = p & 7;
    int l  = (p >> 3) & 63;
    int nt = (p >> 9) % 12;
    int kt = p / (12 * 512);
    int w  = nt >> 2;
    const float* src = (w == 0) ? wq : ((w == 1) ? wk : wv);
    int h = (nt & 3) * 16 + (l & 15);
    int c = kt * 32 + ((l >> 4) << 3) + j;
    wpk[p] = f2bf(src[h * 512 + c]);
}

// ---- fused: one block per batch element; 8 waves; 512 blocks ----
__launch_bounds__(512, 4)
__global__ void attn_fused_kernel(const float* __restrict__ x,
                                  const ushort* __restrict__ wpk,
                                  float* __restrict__ out) {
    // 56 KB LDS union -> 2 blocks/CU.
    // projection phase: [0,24576) W dbuf (2x12KB), [24576,57344) x dbuf (2x16KB)
    // attention phase:  [0,16384) qs, [16384,32768) ks, [32768,49152) vst,
    //                   ps = [0,32768) overlay of qs+ks.
    __shared__ __align__(16) char smem[57344];
    ushort* qs  = (ushort*)smem;               // [128][64] swizzled col^((t&7)<<3)
    ushort* ks  = (ushort*)(smem + 16384);     // [128][64] swizzled
    ushort* vst = (ushort*)(smem + 32768);     // [64][128] V^T, swizzled t^((h&7)<<3)
    ushort* ps  = (ushort*)smem;               // [128][128] P overlay, swizzled

    const int tid  = threadIdx.x;
    const int wave = tid >> 6;
    const int lane = tid & 63;
    const int lq   = lane >> 4;
    const int lr   = lane & 15;
    const int b    = blockIdx.x;
    const size_t bB = (size_t)b * TT;          // first global row of this batch

    const f32x4 fzero = {0.f, 0.f, 0.f, 0.f};

    // ================= Phase 1: QKV projection =================
    f32x4 acc[12];
    #pragma unroll
    for (int j = 0; j < 12; ++j) acc[j] = fzero;

    auto stage = [&](int kt, int s) {
        // W slab 12 KB: 8 waves x 1KB + waves 0-3 x 1KB
        const char* wsrc = (const char*)(wpk + kt * 6144);
        char* wdst = smem + s * 12288;
        {
            int off = wave * 1024;
            gload_lds16(wsrc + off + lane * 16, wdst + off);
            if (wave < 4) {
                int off2 = 8192 + wave * 1024;
                gload_lds16(wsrc + off2 + lane * 16, wdst + off2);
            }
        }
        // x slab 16 KB = 128 rows x 128 B, swizzled source (slot ^ (row&7))
        char* xdst = smem + 24576 + s * 16384;
        #pragma unroll
        for (int p = 0; p < 2; ++p) {
            int uoff = wave * 2048 + p * 1024;              // uniform
            int off  = uoff + lane * 16;                    // per-lane
            int row  = off >> 7;
            int slot = (off >> 4) & 7;
            int g    = slot ^ (row & 7);
            const float* src = x + (bB + row) * CC + kt * 32 + g * 4;
            gload_lds16(src, xdst + uoff);
        }
    };

    stage(0, 0);
    __syncthreads();

    const int r = wave * 16 + lr;              // block-local row this lane reads
    for (int kt = 0; kt < 16; ++kt) {
        const int cur = kt & 1;
        if (kt + 1 < 16) stage(kt + 1, cur ^ 1);

        const float* xs = (const float*)(smem + 24576 + cur * 16384);
        int s0 = (lq * 2) ^ (r & 7);
        int s1 = (lq * 2 + 1) ^ (r & 7);
        f32x4 alo = *(const f32x4*)(xs + r * 32 + s0 * 4);
        f32x4 ahi = *(const f32x4*)(xs + r * 32 + s1 * 4);
        bf16x8 a;
        a[0] = (short)f2bf(alo[0]); a[1] = (short)f2bf(alo[1]);
        a[2] = (short)f2bf(alo[2]); a[3] = (short)f2bf(alo[3]);
        a[4] = (short)f2bf(ahi[0]); a[5] = (short)f2bf(ahi[1]);
        a[6] = (short)f2bf(ahi[2]); a[7] = (short)f2bf(ahi[3]);

        const ushort* wf = (const ushort*)(smem + cur * 12288);
        #pragma unroll
        for (int nt = 0; nt < 12; ++nt) {
            bf16x8 bb = *(const bf16x8*)(wf + (nt * 64 + lane) * 8);
            acc[nt] = __builtin_amdgcn_mfma_f32_16x16x32_bf16(a, bb, acc[nt], 0, 0, 0);
        }
        __syncthreads();   // also drains vmcnt before buffer reuse / epilogue
    }

    // ---- QKV -> attention LDS (overlays staging buffers; safe post-barrier)
    #pragma unroll
    for (int nt = 0; nt < 12; ++nt)
        #pragma unroll
        for (int j = 0; j < 4; ++j) {
            int t = wave * 16 + lq * 4 + j;
            int h = (nt & 3) * 16 + lr;
            ushort v = f2bf(acc[nt][j]);
            if (nt < 4)      qs[t * 64 + (h ^ ((t & 7) << 3))] = v;
            else if (nt < 8) ks[t * 64 + (h ^ ((t & 7) << 3))] = v;
            else             vst[h * 128 + (t ^ ((h & 7) << 3))] = v;
        }
    __syncthreads();

    // ================= Phase 2: S = Q K^T, causal softmax =================
    const int row0 = wave * 16;
    f32x4 s[8];
    #pragma unroll
    for (int j = 0; j < 8; ++j) s[j] = fzero;

    #pragma unroll
    for (int kt = 0; kt < 2; ++kt) {
        int h0 = kt * 32 + lq * 8;
        int t  = row0 + lr;
        bf16x8 a = *(const bf16x8*)&qs[t * 64 + (h0 ^ ((t & 7) << 3))];
        #pragma unroll
        for (int nt = 0; nt < 8; ++nt) {
            int sc = nt * 16 + lr;
            bf16x8 bb = *(const bf16x8*)&ks[sc * 64 + (h0 ^ ((sc & 7) << 3))];
            s[nt] = __builtin_amdgcn_mfma_f32_16x16x32_bf16(a, bb, s[nt], 0, 0, 0);
        }
    }

    float rinv[4];
    #pragma unroll
    for (int j = 0; j < 4; ++j) {
        int t = row0 + lq * 4 + j;
        float m = -1e30f;
        #pragma unroll
        for (int nt = 0; nt < 8; ++nt) {
            int sc = nt * 16 + lr;
            float v = s[nt][j] * 0.125f;
            v = (sc <= t) ? v : -1e30f;        // causal mask
            s[nt][j] = v;
            m = fmaxf(m, v);
        }
        m = fmaxf(m, __shfl_xor(m, 1));
        m = fmaxf(m, __shfl_xor(m, 2));
        m = fmaxf(m, __shfl_xor(m, 4));
        m = fmaxf(m, __shfl_xor(m, 8));
        float sum = 0.f;
        #pragma unroll
        for (int nt = 0; nt < 8; ++nt) {
            float p = __expf(s[nt][j] - m);
            s[nt][j] = p;
            sum += p;
        }
        sum += __shfl_xor(sum, 1);
        sum += __shfl_xor(sum, 2);
        sum += __shfl_xor(sum, 4);
        sum += __shfl_xor(sum, 8);
        rinv[j] = 1.0f / sum;                  // deferred normalization
    }

    __syncthreads();   // all qs/ks reads done before P overlay writes

    #pragma unroll
    for (int j = 0; j < 4; ++j) {
        int t = row0 + lq * 4 + j;
        #pragma unroll
        for (int nt = 0; nt < 8; ++nt) {
            int sc = nt * 16 + lr;
            ps[t * 128 + (sc ^ ((t & 7) << 3))] = f2bf(s[nt][j]);
        }
    }
    __syncthreads();

    // ================= Phase 3: O = P V =================
    f32x4 o[4];
    #pragma unroll
    for (int j = 0; j < 4; ++j) o[j] = fzero;

    #pragma unroll
    for (int ksv = 0; ksv < 4; ++ksv) {
        int s0 = ksv * 32 + lq * 8;
        int t  = row0 + lr;
        bf16x8 a = *(const bf16x8*)&ps[t * 128 + (s0 ^ ((t & 7) << 3))];
        #pragma unroll
        for (int nt = 0; nt < 4; ++nt) {
            int h = nt * 16 + lr;
            bf16x8 bb = *(const bf16x8*)&vst[h * 128 + (s0 ^ ((h & 7) << 3))];
            o[nt] = __builtin_amdgcn_mfma_f32_16x16x32_bf16(a, bb, o[nt], 0, 0, 0);
        }
    }

    float* ob = out + (size_t)b * (TT * HH);
    #pragma unroll
    for (int nt = 0; nt < 4; ++nt)
        #pragma unroll
        for (int j = 0; j < 4; ++j) {
            int t = row0 + lq * 4 + j;
            int h = nt * 16 + lr;
            ob[t * HH + h] = o[nt][j] * rinv[j];
        }
}

extern "C" void kernel_launch(void* const* d_in, const int* in_sizes, int n_in,
                              void* d_out, int out_size, void* d_ws, size_t ws_size,
                              hipStream_t stream) {
    const float* x  = (const float*)d_in[0];
    const float* wq = (const float*)d_in[1];
    const float* wk = (const float*)d_in[2];
    const float* wv = (const float*)d_in[3];
    float* o = (float*)d_out;
    ushort* wpk = (ushort*)d_ws;    // 192 KB packed W fragments

    (void)in_sizes; (void)n_in; (void)out_size; (void)ws_size;

    wpack_kernel<<<384, 256, 0, stream>>>(wq, wk, wv, wpk);
    attn_fused_kernel<<<512, 512, 0, stream>>>(x, wpk, o);
}

// Round 9
// 38.576 us; speedup vs baseline: 2.2312x; 1.0039x over previous
//
#include <hip/hip_runtime.h>
#include <hip/hip_bf16.h>

// Attention: B=512, T=128, C=512, H=64. out[b,t,h] f32.
// R9: R8 fused kernel + T4 counted-vmcnt pipeline (raw s_barrier, never
// vmcnt(0) in the main loop). W chunks padded to 16KB so every wave issues
// exactly 4 global_load_lds per stage -> uniform s_waitcnt vmcnt(4).
// LDS 64KB union: staging Wdbuf 2x16K | xdbuf 2x16K; attention qs|ks|vst
// overlays. 2 blocks/CU.

#define TT 128
#define CC 512
#define HH 64

typedef __attribute__((ext_vector_type(8))) short bf16x8;
typedef __attribute__((ext_vector_type(4))) float f32x4;

__device__ __forceinline__ ushort f2bf(float f) {
    union { float f; unsigned u; } v; v.f = f;
    unsigned r = v.u + 0x7fffu + ((v.u >> 16) & 1u);  // RNE
    return (ushort)(r >> 16);
}

__device__ __forceinline__ void gload_lds16(const void* g, void* l) {
    __builtin_amdgcn_global_load_lds(
        (const __attribute__((address_space(1))) unsigned int*)g,
        (__attribute__((address_space(3))) unsigned int*)l, 16, 0, 0);
}

// ---- wpack: chunk kt stride 8192 ushorts (16KB, last 4KB pad unused) ----
// idx = kt*8192 + (nt*64+lane)*8 + j ;  value = W_{nt>>2}[h][c],
// h = (nt&3)*16 + (lane&15), c = kt*32 + (lane>>4)*8 + j
__global__ void wpack_kernel(const float* __restrict__ wq,
                             const float* __restrict__ wk,
                             const float* __restrict__ wv,
                             ushort* __restrict__ wpk) {
    int p = blockIdx.x * 256 + threadIdx.x;   // 0..98303
    int j  = p & 7;
    int l  = (p >> 3) & 63;
    int nt = (p >> 9) % 12;
    int kt = p / (12 * 512);
    int w  = nt >> 2;
    const float* src = (w == 0) ? wq : ((w == 1) ? wk : wv);
    int h = (nt & 3) * 16 + (l & 15);
    int c = kt * 32 + ((l >> 4) << 3) + j;
    wpk[kt * 8192 + ((nt * 64 + l) * 8) + j] = f2bf(src[h * 512 + c]);
}

// ---- fused: one block per batch element; 8 waves; 512 blocks ----
__launch_bounds__(512, 4)
__global__ void attn_fused_kernel(const float* __restrict__ x,
                                  const ushort* __restrict__ wpk,
                                  float* __restrict__ out) {
    // 64 KB LDS union -> 2 blocks/CU.
    // staging:   [0,32768) W dbuf (2x16KB), [32768,65536) x dbuf (2x16KB)
    // attention: [0,16384) qs, [16384,32768) ks, [32768,49152) vst,
    //            ps = [0,32768) overlay.
    __shared__ __align__(16) char smem[65536];
    ushort* qs  = (ushort*)smem;               // [128][64] swizzled col^((t&7)<<3)
    ushort* ks  = (ushort*)(smem + 16384);     // [128][64] swizzled
    ushort* vst = (ushort*)(smem + 32768);     // [64][128] V^T, swizzled t^((h&7)<<3)
    ushort* ps  = (ushort*)smem;               // [128][128] P overlay, swizzled

    const int tid  = threadIdx.x;
    const int wave = tid >> 6;
    const int lane = tid & 63;
    const int lq   = lane >> 4;
    const int lr   = lane & 15;
    const int b    = blockIdx.x;
    const size_t bB = (size_t)b * TT;          // first global row of this batch

    const f32x4 fzero = {0.f, 0.f, 0.f, 0.f};

    // ================= Phase 1: QKV projection =================
    f32x4 acc[12];
    #pragma unroll
    for (int j = 0; j < 12; ++j) acc[j] = fzero;

    // every wave issues EXACTLY 4 global_load_lds per stage (2 W + 2 x)
    auto stage = [&](int kt, int s) {
        // W slab 16KB (12KB data + 4KB pad)
        const char* wsrc = (const char*)(wpk + kt * 8192);
        char* wdst = smem + s * 16384;
        #pragma unroll
        for (int p = 0; p < 2; ++p) {
            int off = wave * 2048 + p * 1024;               // uniform in wave
            gload_lds16(wsrc + off + lane * 16, wdst + off);
        }
        // x slab 16KB = 128 rows x 128 B, swizzled source (slot ^ (row&7))
        char* xdst = smem + 32768 + s * 16384;
        #pragma unroll
        for (int p = 0; p < 2; ++p) {
            int uoff = wave * 2048 + p * 1024;              // uniform
            int off  = uoff + lane * 16;                    // per-lane
            int row  = off >> 7;
            int slot = (off >> 4) & 7;
            int g    = slot ^ (row & 7);
            const float* src = x + (bB + row) * CC + kt * 32 + g * 4;
            gload_lds16(src, xdst + uoff);
        }
    };

    stage(0, 0);

    const int r = wave * 16 + lr;              // block-local row this lane reads
    for (int kt = 0; kt < 16; ++kt) {
        const int cur = kt & 1;

        // barrier 1: all waves finished compute(kt-1) -> safe to overwrite
        // buf[cur^1] with stage(kt+1)'s async writes.
        __builtin_amdgcn_s_barrier();

        if (kt + 1 < 16) {
            stage(kt + 1, cur ^ 1);
            // retire stage(kt)'s 4 loads (issued one full compute-phase ago);
            // keep stage(kt+1)'s 4 in flight across the barrier (T4).
            asm volatile("s_waitcnt vmcnt(4)" ::: "memory");
        } else {
            asm volatile("s_waitcnt vmcnt(0)" ::: "memory");
        }
        __builtin_amdgcn_sched_barrier(0);

        // barrier 2: every wave's stage(kt) data now visible in LDS.
        __builtin_amdgcn_s_barrier();
        __builtin_amdgcn_sched_barrier(0);

        const float* xs = (const float*)(smem + 32768 + cur * 16384);
        int s0 = (lq * 2) ^ (r & 7);
        int s1 = (lq * 2 + 1) ^ (r & 7);
        f32x4 alo = *(const f32x4*)(xs + r * 32 + s0 * 4);
        f32x4 ahi = *(const f32x4*)(xs + r * 32 + s1 * 4);
        bf16x8 a;
        a[0] = (short)f2bf(alo[0]); a[1] = (short)f2bf(alo[1]);
        a[2] = (short)f2bf(alo[2]); a[3] = (short)f2bf(alo[3]);
        a[4] = (short)f2bf(ahi[0]); a[5] = (short)f2bf(ahi[1]);
        a[6] = (short)f2bf(ahi[2]); a[7] = (short)f2bf(ahi[3]);

        const ushort* wf = (const ushort*)(smem + cur * 16384);
        #pragma unroll
        for (int nt = 0; nt < 12; ++nt) {
            bf16x8 bb = *(const bf16x8*)(wf + (nt * 64 + lane) * 8);
            acc[nt] = __builtin_amdgcn_mfma_f32_16x16x32_bf16(a, bb, acc[nt], 0, 0, 0);
        }
    }

    __syncthreads();   // compute(15) done everywhere before overlay writes

    // ---- QKV -> attention LDS (overlays staging buffers) ----
    #pragma unroll
    for (int nt = 0; nt < 12; ++nt)
        #pragma unroll
        for (int j = 0; j < 4; ++j) {
            int t = wave * 16 + lq * 4 + j;
            int h = (nt & 3) * 16 + lr;
            ushort v = f2bf(acc[nt][j]);
            if (nt < 4)      qs[t * 64 + (h ^ ((t & 7) << 3))] = v;
            else if (nt < 8) ks[t * 64 + (h ^ ((t & 7) << 3))] = v;
            else             vst[h * 128 + (t ^ ((h & 7) << 3))] = v;
        }
    __syncthreads();

    // ================= Phase 2: S = Q K^T, causal softmax =================
    const int row0 = wave * 16;
    f32x4 s[8];
    #pragma unroll
    for (int j = 0; j < 8; ++j) s[j] = fzero;

    #pragma unroll
    for (int kt = 0; kt < 2; ++kt) {
        int h0 = kt * 32 + lq * 8;
        int t  = row0 + lr;
        bf16x8 a = *(const bf16x8*)&qs[t * 64 + (h0 ^ ((t & 7) << 3))];
        #pragma unroll
        for (int nt = 0; nt < 8; ++nt) {
            int sc = nt * 16 + lr;
            bf16x8 bb = *(const bf16x8*)&ks[sc * 64 + (h0 ^ ((sc & 7) << 3))];
            s[nt] = __builtin_amdgcn_mfma_f32_16x16x32_bf16(a, bb, s[nt], 0, 0, 0);
        }
    }

    float rinv[4];
    #pragma unroll
    for (int j = 0; j < 4; ++j) {
        int t = row0 + lq * 4 + j;
        float m = -1e30f;
        #pragma unroll
        for (int nt = 0; nt < 8; ++nt) {
            int sc = nt * 16 + lr;
            float v = s[nt][j] * 0.125f;
            v = (sc <= t) ? v : -1e30f;        // causal mask
            s[nt][j] = v;
            m = fmaxf(m, v);
        }
        m = fmaxf(m, __shfl_xor(m, 1));
        m = fmaxf(m, __shfl_xor(m, 2));
        m = fmaxf(m, __shfl_xor(m, 4));
        m = fmaxf(m, __shfl_xor(m, 8));
        float sum = 0.f;
        #pragma unroll
        for (int nt = 0; nt < 8; ++nt) {
            float p = __expf(s[nt][j] - m);
            s[nt][j] = p;
            sum += p;
        }
        sum += __shfl_xor(sum, 1);
        sum += __shfl_xor(sum, 2);
        sum += __shfl_xor(sum, 4);
        sum += __shfl_xor(sum, 8);
        rinv[j] = 1.0f / sum;                  // deferred normalization
    }

    __syncthreads();   // all qs/ks reads done before P overlay writes

    #pragma unroll
    for (int j = 0; j < 4; ++j) {
        int t = row0 + lq * 4 + j;
        #pragma unroll
        for (int nt = 0; nt < 8; ++nt) {
            int sc = nt * 16 + lr;
            ps[t * 128 + (sc ^ ((t & 7) << 3))] = f2bf(s[nt][j]);
        }
    }
    __syncthreads();

    // ================= Phase 3: O = P V =================
    f32x4 o[4];
    #pragma unroll
    for (int j = 0; j < 4; ++j) o[j] = fzero;

    #pragma unroll
    for (int ksv = 0; ksv < 4; ++ksv) {
        int s0 = ksv * 32 + lq * 8;
        int t  = row0 + lr;
        bf16x8 a = *(const bf16x8*)&ps[t * 128 + (s0 ^ ((t & 7) << 3))];
        #pragma unroll
        for (int nt = 0; nt < 4; ++nt) {
            int h = nt * 16 + lr;
            bf16x8 bb = *(const bf16x8*)&vst[h * 128 + (s0 ^ ((h & 7) << 3))];
            o[nt] = __builtin_amdgcn_mfma_f32_16x16x32_bf16(a, bb, o[nt], 0, 0, 0);
        }
    }

    float* ob = out + (size_t)b * (TT * HH);
    #pragma unroll
    for (int nt = 0; nt < 4; ++nt)
        #pragma unroll
        for (int j = 0; j < 4; ++j) {
            int t = row0 + lq * 4 + j;
            int h = nt * 16 + lr;
            ob[t * HH + h] = o[nt][j] * rinv[j];
        }
}

extern "C" void kernel_launch(void* const* d_in, const int* in_sizes, int n_in,
                              void* d_out, int out_size, void* d_ws, size_t ws_size,
                              hipStream_t stream) {
    const float* x  = (const float*)d_in[0];
    const float* wq = (const float*)d_in[1];
    const float* wk = (const float*)d_in[2];
    const float* wv = (const float*)d_in[3];
    float* o = (float*)d_out;
    ushort* wpk = (ushort*)d_ws;    // 16 chunks x 16KB = 256 KB packed W

    (void)in_sizes; (void)n_in; (void)out_size; (void)ws_size;

    wpack_kernel<<<384, 256, 0, stream>>>(wq, wk, wv, wpk);
    attn_fused_kernel<<<512, 512, 0, stream>>>(x, wpk, o);
}